// Round 23
// baseline (465.697 us; speedup 1.0000x reference)
//
#include <hip/hip_runtime.h>
#include <hip/hip_bf16.h>

// u[b,o,y,x] = sum_d dist(p,d) * t[b,d,o],  t = v@W^T + bias
// GEMM: out[col*9216 + p] = sum_d D[p,d] * T2[col][d],  col = b*32+o
// R20-passing gemm text (dup=1: 4 waves x 32 rows, all 256 cols, acc 1x8,
// perm-pack agen, BK=64, 8-slot swizzle, 2x32KB dbuf, __syncthreads).
// CHANGE: no f16 partials / reduce kernel -- gemm atomically accumulates
// f32 into out (memsetAsync first). Saves 66MB of partial round-trip +
// one dispatch. NSPLIT=7, grid 504.

typedef __bf16    bf16x8 __attribute__((ext_vector_type(8)));
typedef float     f32x4  __attribute__((ext_vector_type(4)));
typedef float     f32x16 __attribute__((ext_vector_type(16)));

#define NPTS   9216      // 96*96
#define CIN    32
#define COUT   32
#define NCOLS  256       // 8 batches * 32 cout
#define SCALE  (1.0f / 95.0f)
#define OUTN   (NCOLS * NPTS)
#define NSPLIT 7
#define KCHUNK 1344      // 14*96 (last chunk 1152 = 12*96)

// ---------------- Kernel 1: projection  T2[col][d] = bf16(v . W^T + b) ----
__global__ __launch_bounds__(256) void proj_kernel(
    const float* __restrict__ v, const float* __restrict__ W,
    const float* __restrict__ bias, __bf16* __restrict__ T2)
{
    __shared__ float Wl[COUT * CIN];
    __shared__ float bl[COUT];
    const int t = threadIdx.x;
    for (int i = t; i < COUT * CIN; i += 256) Wl[i] = W[i];
    if (t < COUT) bl[t] = bias[t];
    __syncthreads();

    const int b = blockIdx.y;
    const int d = blockIdx.x * 256 + t;
    const float* vb = v + (size_t)b * CIN * NPTS + d;

    float acc[COUT];
#pragma unroll
    for (int o = 0; o < COUT; ++o) acc[o] = bl[o];
#pragma unroll 4
    for (int c = 0; c < CIN; ++c) {
        const float vv = vb[(size_t)c * NPTS];
#pragma unroll
        for (int o = 0; o < COUT; ++o) acc[o] += vv * Wl[o * CIN + c];
    }
#pragma unroll
    for (int o = 0; o < COUT; ++o)
        T2[(size_t)(b * COUT + o) * NPTS + d] = (__bf16)acc[o];
}

// ---------------- A-fragment generator (perm-pack, proven) ---------------
__device__ __forceinline__ bf16x8 agen(float dx, float dy2) {
    float f[8];
#pragma unroll
    for (int j = 0; j < 8; ++j) {
        f[j] = __builtin_amdgcn_sqrtf(__builtin_fmaf(dx, dx, dy2));
        dx -= SCALE;
    }
    union { unsigned int u[4]; bf16x8 v; } pk;
#pragma unroll
    for (int q = 0; q < 4; ++q) {
        const unsigned int lo = __builtin_bit_cast(unsigned int, f[2*q])   + 0x8000u;
        const unsigned int hi = __builtin_bit_cast(unsigned int, f[2*q+1]) + 0x8000u;
        pk.u[q] = __builtin_amdgcn_perm(hi, lo, 0x07060302u);  // [hi16(hi)|hi16(lo)]
    }
    return pk.v;
}

// ---------------- Kernel 2: implicit-D GEMM (dup=1, atomic epilogue) -----
__global__ __launch_bounds__(256, 2) void gemm_kernel(
    const __bf16* __restrict__ T2, float* __restrict__ out)
{
    __shared__ __align__(1024) unsigned char lds[2][32768];

    const int tid  = threadIdx.x;
    const int wid  = tid >> 6;
    const int lane = tid & 63;
    const int l31  = lane & 31;
    const int hi   = lane >> 5;      // k-half within frag

    const int bid = blockIdx.x;
    const int z   = bid / 72;        // k-chunk id 0..6
    const int x   = bid - z * 72;    // row-block id 0..71
    const int koff = z * KCHUNK;
    const int nt   = (z == NSPLIT - 1) ? 18 : 21;   // BK=64 tiles

    // dup=1: each wave owns 32 rows (wid*32), covers all 256 cols
    const int pbase = x * 128 + wid * 32;
    const int prow  = pbase + l31;   // this lane's A row
    const int yp = prow / 96, xp = prow - yp * 96;
    const int xph = xp - hi * 8;     // hi fold pre-applied

    // hoisted LDS B-read byte offsets boff[s][n] (lane-constant), n=0..7
    int boff[4][8];
#pragma unroll
    for (int s = 0; s < 4; ++s)
#pragma unroll
        for (int n = 0; n < 8; ++n) {
            const int col  = n * 32 + l31;
            const int slot = (s * 2 + hi) ^ (col & 7);
            boff[s][n] = col * 128 + slot * 16;
        }

    // staging: 8 x gload16 per buffer; dest linear tid*16 within 4KB rows;
    // source chunk pre-swizzled so LDS slot = logical ^ (col&7).
    const int scol = tid >> 3;               // col 0..31 (+32*i)
    const int sch  = (tid & 7) ^ (scol & 7);
    const __bf16* gsrc = T2 + (size_t)scol * NPTS + koff + sch * 8;
    const int ldst = tid * 16;

    auto stage = [&](int buf, int kt) {
#pragma unroll
        for (int i = 0; i < 8; ++i)
            __builtin_amdgcn_global_load_lds(
                (const __attribute__((address_space(1))) void*)
                    (gsrc + (size_t)kt * 64 + (size_t)i * 32 * NPTS),
                (__attribute__((address_space(3))) void*)
                    (&lds[buf][i * 4096 + ldst]),
                16, 0, 0);
    };

    f32x16 acc[8];
#pragma unroll
    for (int n = 0; n < 8; ++n) acc[n] = (f32x16)(0.0f);

    stage(0, 0);
    __syncthreads();

    int xt = 0, yt = z * 14;         // k-tile base coords (koff%96==0)
    int cur = 0;
    for (int kt = 0; kt < nt; ++kt) {
        if (kt + 1 < nt) stage(cur ^ 1, kt + 1);
        const unsigned char* Lb = lds[cur];

#pragma unroll
        for (int s = 0; s < 4; ++s) {        // 4 k-steps of 16
            const int xr = xt + s * 16;
            const int xk = (xr >= 96) ? xr - 96 : xr;
            const int yk = (xr >= 96) ? yt + 1  : yt;
            const float dy = (float)(yp - yk) * SCALE;
            const bf16x8 a = agen((float)(xph - xk) * SCALE, dy * dy);
#pragma unroll
            for (int n = 0; n < 8; ++n) {
                const bf16x8 b = *(const bf16x8*)(Lb + boff[s][n]);
                acc[n] = __builtin_amdgcn_mfma_f32_32x32x16_bf16(
                    a, b, acc[n], 0, 0, 0);
            }
        }
        xt += 64; if (xt >= 96) { xt -= 96; ++yt; }
        __syncthreads();
        cur ^= 1;
    }

    // epilogue: 32x32 C/D: col=lane&31, row=(r&3)+8*(r>>2)+4*hi
    // direct f32 atomic accumulation into out (7 k-chunks per location)
#pragma unroll
    for (int n = 0; n < 8; ++n) {
        const int col = n * 32 + l31;
        float* ob = out + (size_t)col * NPTS + pbase + 4 * hi;
#pragma unroll
        for (int q = 0; q < 4; ++q)
#pragma unroll
            for (int r = 0; r < 4; ++r)
                atomicAdd(ob + q * 8 + r, acc[n][4*q+r]);
    }
}

extern "C" void kernel_launch(void* const* d_in, const int* in_sizes, int n_in,
                              void* d_out, int out_size, void* d_ws, size_t ws_size,
                              hipStream_t stream) {
    const float* v    = (const float*)d_in[0];  // (8,32,96,96)
    const float* W    = (const float*)d_in[1];  // (32,32)
    const float* bias = (const float*)d_in[2];  // (32,)
    float* out = (float*)d_out;                 // (8,32,96,96) f32

    __bf16* T2 = (__bf16*)d_ws;                 // 256 x 9216 bf16 = 4.72 MB

    hipMemsetAsync(d_out, 0, (size_t)out_size * sizeof(float), stream);
    proj_kernel<<<dim3(36, 8), 256, 0, stream>>>(v, W, bias, T2);
    gemm_kernel<<<72 * NSPLIT, 256, 0, stream>>>(T2, out);
}

// Round 24
// 78.589 us; speedup vs baseline: 5.9257x; 5.9257x over previous
//
#include <hip/hip_runtime.h>
#include <hip/hip_bf16.h>

// u[b,o,y,x] = sum_d dist(p,d) * t[b,d,o],  t = v@W^T + bias
// GEMM: out[col*9216 + p] = sum_d D[p,d] * T2[col][d],  col = b*32+o
// FINAL (R20 reproduction): dup=1 structure -- 4 waves each own 32 rows x
// ALL 256 cols (acc 1x8 = 128 AGPR; chip-wide sqrt work = 1x), perm-pack
// agen, 32x32x16 bf16 MFMA, tile 128r x 256c, BK=64 dbuf (64KB LDS),
// NSPLIT=7 (grid 504, single resident pass), f16 partials + reduce.
// Measured: 78.7us total, gemm 58.4us, absmax 2.0.

typedef __bf16    bf16x8 __attribute__((ext_vector_type(8)));
typedef float     f32x4  __attribute__((ext_vector_type(4)));
typedef float     f32x16 __attribute__((ext_vector_type(16)));
typedef _Float16  f16x4  __attribute__((ext_vector_type(4)));
typedef _Float16  f16x8  __attribute__((ext_vector_type(8)));

#define NPTS   9216      // 96*96
#define CIN    32
#define COUT   32
#define NCOLS  256       // 8 batches * 32 cout
#define SCALE  (1.0f / 95.0f)
#define OUTN   (NCOLS * NPTS)
#define NSPLIT 7
#define KCHUNK 1344      // 14*96 (last chunk 1152 = 12*96)

// ---------------- Kernel 1: projection  T2[col][d] = bf16(v . W^T + b) ----
__global__ __launch_bounds__(256) void proj_kernel(
    const float* __restrict__ v, const float* __restrict__ W,
    const float* __restrict__ bias, __bf16* __restrict__ T2)
{
    __shared__ float Wl[COUT * CIN];
    __shared__ float bl[COUT];
    const int t = threadIdx.x;
    for (int i = t; i < COUT * CIN; i += 256) Wl[i] = W[i];
    if (t < COUT) bl[t] = bias[t];
    __syncthreads();

    const int b = blockIdx.y;
    const int d = blockIdx.x * 256 + t;
    const float* vb = v + (size_t)b * CIN * NPTS + d;

    float acc[COUT];
#pragma unroll
    for (int o = 0; o < COUT; ++o) acc[o] = bl[o];
#pragma unroll 4
    for (int c = 0; c < CIN; ++c) {
        const float vv = vb[(size_t)c * NPTS];
#pragma unroll
        for (int o = 0; o < COUT; ++o) acc[o] += vv * Wl[o * CIN + c];
    }
#pragma unroll
    for (int o = 0; o < COUT; ++o)
        T2[(size_t)(b * COUT + o) * NPTS + d] = (__bf16)acc[o];
}

// ---------------- A-fragment generator (perm-pack, proven) ---------------
__device__ __forceinline__ bf16x8 agen(float dx, float dy2) {
    float f[8];
#pragma unroll
    for (int j = 0; j < 8; ++j) {
        f[j] = __builtin_amdgcn_sqrtf(__builtin_fmaf(dx, dx, dy2));
        dx -= SCALE;
    }
    union { unsigned int u[4]; bf16x8 v; } pk;
#pragma unroll
    for (int q = 0; q < 4; ++q) {
        const unsigned int lo = __builtin_bit_cast(unsigned int, f[2*q])   + 0x8000u;
        const unsigned int hi = __builtin_bit_cast(unsigned int, f[2*q+1]) + 0x8000u;
        pk.u[q] = __builtin_amdgcn_perm(hi, lo, 0x07060302u);  // [hi16(hi)|hi16(lo)]
    }
    return pk.v;
}

// ---------------- Kernel 2: implicit-D GEMM (dup=1) ----------------------
__global__ __launch_bounds__(256, 2) void gemm_kernel(
    const __bf16* __restrict__ T2, void* __restrict__ dst, int usePartial)
{
    __shared__ __align__(1024) unsigned char lds[2][32768];

    const int tid  = threadIdx.x;
    const int wid  = tid >> 6;
    const int lane = tid & 63;
    const int l31  = lane & 31;
    const int hi   = lane >> 5;      // k-half within frag

    const int bid = blockIdx.x;
    const int z   = bid / 72;        // k-chunk id 0..6
    const int x   = bid - z * 72;    // row-block id 0..71
    const int koff = z * KCHUNK;
    const int nt   = (z == NSPLIT - 1) ? 18 : 21;   // BK=64 tiles

    // dup=1: each wave owns 32 rows (wid*32), covers all 256 cols
    const int pbase = x * 128 + wid * 32;
    const int prow  = pbase + l31;   // this lane's A row
    const int yp = prow / 96, xp = prow - yp * 96;
    const int xph = xp - hi * 8;     // hi fold pre-applied

    // hoisted LDS B-read byte offsets boff[s][n] (lane-constant), n=0..7
    int boff[4][8];
#pragma unroll
    for (int s = 0; s < 4; ++s)
#pragma unroll
        for (int n = 0; n < 8; ++n) {
            const int col  = n * 32 + l31;
            const int slot = (s * 2 + hi) ^ (col & 7);
            boff[s][n] = col * 128 + slot * 16;
        }

    // staging: 8 x gload16 per buffer; dest linear tid*16 within 4KB rows;
    // source chunk pre-swizzled so LDS slot = logical ^ (col&7).
    const int scol = tid >> 3;               // col 0..31 (+32*i)
    const int sch  = (tid & 7) ^ (scol & 7);
    const __bf16* gsrc = T2 + (size_t)scol * NPTS + koff + sch * 8;
    const int ldst = tid * 16;

    auto stage = [&](int buf, int kt) {
#pragma unroll
        for (int i = 0; i < 8; ++i)
            __builtin_amdgcn_global_load_lds(
                (const __attribute__((address_space(1))) void*)
                    (gsrc + (size_t)kt * 64 + (size_t)i * 32 * NPTS),
                (__attribute__((address_space(3))) void*)
                    (&lds[buf][i * 4096 + ldst]),
                16, 0, 0);
    };

    f32x16 acc[8];
#pragma unroll
    for (int n = 0; n < 8; ++n) acc[n] = (f32x16)(0.0f);

    stage(0, 0);
    __syncthreads();

    int xt = 0, yt = z * 14;         // k-tile base coords (koff%96==0)
    int cur = 0;
    for (int kt = 0; kt < nt; ++kt) {
        if (kt + 1 < nt) stage(cur ^ 1, kt + 1);
        const unsigned char* Lb = lds[cur];

#pragma unroll
        for (int s = 0; s < 4; ++s) {        // 4 k-steps of 16
            const int xr = xt + s * 16;
            const int xk = (xr >= 96) ? xr - 96 : xr;
            const int yk = (xr >= 96) ? yt + 1  : yt;
            const float dy = (float)(yp - yk) * SCALE;
            const bf16x8 a = agen((float)(xph - xk) * SCALE, dy * dy);
#pragma unroll
            for (int n = 0; n < 8; ++n) {
                const bf16x8 b = *(const bf16x8*)(Lb + boff[s][n]);
                acc[n] = __builtin_amdgcn_mfma_f32_32x32x16_bf16(
                    a, b, acc[n], 0, 0, 0);
            }
        }
        xt += 64; if (xt >= 96) { xt -= 96; ++yt; }
        __syncthreads();
        cur ^= 1;
    }

    // epilogue: 32x32 C/D: col=lane&31, row=(r&3)+8*(r>>2)+4*hi
    if (usePartial) {
        _Float16* pb = (_Float16*)dst + (size_t)z * OUTN;
#pragma unroll
        for (int n = 0; n < 8; ++n) {
            const int col = n * 32 + l31;
            _Float16* ob = pb + (size_t)col * NPTS + pbase + 4 * hi;
#pragma unroll
            for (int q = 0; q < 4; ++q) {
                f16x4 h = { (_Float16)acc[n][4*q],
                            (_Float16)acc[n][4*q+1],
                            (_Float16)acc[n][4*q+2],
                            (_Float16)acc[n][4*q+3] };
                *(f16x4*)(ob + q * 8) = h;
            }
        }
    } else {
        float* ob0 = (float*)dst;
#pragma unroll
        for (int n = 0; n < 8; ++n) {
            const int col = n * 32 + l31;
            float* ob = ob0 + (size_t)col * NPTS + pbase + 4 * hi;
#pragma unroll
            for (int q = 0; q < 4; ++q)
#pragma unroll
                for (int r = 0; r < 4; ++r)
                    atomicAdd(ob + q * 8 + r, acc[n][4*q+r]);
        }
    }
}

// ---------------- Kernel 3: reduce NSPLIT f16 partials --------------------
__global__ __launch_bounds__(256) void reduce_kernel(
    const _Float16* __restrict__ part, float* __restrict__ out)
{
    const size_t i = ((size_t)blockIdx.x * 256 + threadIdx.x) * 8;
    float a[8] = {};
#pragma unroll
    for (int s = 0; s < NSPLIT; ++s) {
        f16x8 v = *(const f16x8*)(part + (size_t)s * OUTN + i);
#pragma unroll
        for (int r = 0; r < 8; ++r) a[r] += (float)v[r];
    }
    f32x4 o0 = { a[0], a[1], a[2], a[3] };
    f32x4 o1 = { a[4], a[5], a[6], a[7] };
    *(f32x4*)(out + i)     = o0;
    *(f32x4*)(out + i + 4) = o1;
}

extern "C" void kernel_launch(void* const* d_in, const int* in_sizes, int n_in,
                              void* d_out, int out_size, void* d_ws, size_t ws_size,
                              hipStream_t stream) {
    const float* v    = (const float*)d_in[0];  // (8,32,96,96)
    const float* W    = (const float*)d_in[1];  // (32,32)
    const float* bias = (const float*)d_in[2];  // (32,)
    float* out = (float*)d_out;                 // (8,32,96,96) f32

    __bf16* T2 = (__bf16*)d_ws;                 // 256 x 9216 bf16 = 4.72 MB
    const size_t t2b = (size_t)NCOLS * NPTS * 2;
    _Float16* partial = (_Float16*)((char*)d_ws + t2b);
    const size_t need = t2b + (size_t)NSPLIT * OUTN * 2;  // + 33 MB
    const int usePartial = (ws_size >= need) ? 1 : 0;

    proj_kernel<<<dim3(36, 8), 256, 0, stream>>>(v, W, bias, T2);
    if (usePartial) {
        gemm_kernel<<<72 * NSPLIT, 256, 0, stream>>>(T2, partial, 1);
        reduce_kernel<<<OUTN / 2048, 256, 0, stream>>>(partial, out);
    } else {
        hipMemsetAsync(d_out, 0, (size_t)out_size * sizeof(float), stream);
        gemm_kernel<<<72 * NSPLIT, 256, 0, stream>>>(T2, out, 0);
    }
}